// Round 1
// baseline (1320.915 us; speedup 1.0000x reference)
//
#include <hip/hip_runtime.h>
#include <stdint.h>
#include <math.h>

typedef unsigned short u16;
typedef __attribute__((ext_vector_type(8))) __bf16 bf16x8;
typedef __attribute__((ext_vector_type(4))) float f32x4;
typedef __attribute__((ext_vector_type(4))) unsigned short u16x4;

__device__ __forceinline__ float b2f(u16 u) {
    unsigned int i = ((unsigned int)u) << 16;
    float f; __builtin_memcpy(&f, &i, 4); return f;
}
__device__ __forceinline__ u16 f2b(float f) {
    unsigned int i; __builtin_memcpy(&i, &f, 4);
    i = (i + 0x7FFFu + ((i >> 16) & 1u)) >> 16;   // RNE
    return (u16)i;
}
// load 8 consecutive fp32, convert to bf16x8 (RNE)
__device__ __forceinline__ bf16x8 ld8_cvt(const float* p) {
    float4 f0 = *(const float4*)p, f1 = *(const float4*)(p + 4);
    u16 t[8] = {f2b(f0.x), f2b(f0.y), f2b(f0.z), f2b(f0.w),
                f2b(f1.x), f2b(f1.y), f2b(f1.z), f2b(f1.w)};
    bf16x8 r; __builtin_memcpy(&r, t, 16); return r;
}

// async global->LDS 16B copy (global_load_lds_dwordx4). LDS dest must be
// wave-uniform base + lane*16 — all call sites below satisfy this (offset
// is tid*16 bytes within a 256-thread block => per-wave base + lane*16).
__device__ __forceinline__ void glds16(const u16* g, u16* l) {
    __builtin_amdgcn_global_load_lds(
        (const __attribute__((address_space(1))) void*)g,
        (__attribute__((address_space(3))) void*)l, 16, 0, 0);
}

// ---------------------------------------------------------------------------
// Transpose + fp32->bf16 convert: in[R][C] fp32 -> out[C][R] bf16.
// block (32,8), grid (C/32, R/32)
// ---------------------------------------------------------------------------
__global__ __launch_bounds__(256) void transpose_f32_bf16(
    const float* __restrict__ in, u16* __restrict__ out, int R, int C)
{
    __shared__ float t[32][33];
    int bx = blockIdx.x * 32, by = blockIdx.y * 32;
    int x = threadIdx.x, y = threadIdx.y;
    #pragma unroll
    for (int j = 0; j < 32; j += 8)
        t[y + j][x] = in[(size_t)(by + y + j) * C + bx + x];
    __syncthreads();
    #pragma unroll
    for (int j = 0; j < 32; j += 8)
        out[(size_t)(bx + y + j) * R + by + x] = f2b(t[x][y + j]);
}

// ---------------------------------------------------------------------------
// Elementwise fp32 -> bf16 convert (for x before the QKV GEMM).
// grid*256*8 must equal element count.
// ---------------------------------------------------------------------------
__global__ __launch_bounds__(256) void cvt_f32_bf16(
    const float* __restrict__ in, u16* __restrict__ out)
{
    size_t i = ((size_t)blockIdx.x * 256 + threadIdx.x) * 8;
    *(bf16x8*)(out + i) = ld8_cvt(in + i);
}

// ---------------------------------------------------------------------------
// GEMM: C[M,N] = A[M,K] @ Bt[N,K]^T (+bias, epilogue).  A,Bt bf16; acc fp32.
// EPI 0: C = acc + bias (bf16 out)   EPI 1: C = gelu_erf(acc + bias) (bf16)
// EPI 2: QKV permuted store into q/k/v [8,16,512,64] bf16 with per-matrix bias
// BM=128 x BN(template 128|64) tile, BK=32, 256 threads.
// Staging: global_load_lds width=16 (m97 structure, 2 barriers/K-step).
// BN=64 exists so N=1024 GEMMs get >=512 blocks (>=2 blocks/CU overlap).
// ---------------------------------------------------------------------------
template<int EPI, int BN>
__global__ __launch_bounds__(256) void gemm_bt(
    const u16* __restrict__ A, const u16* __restrict__ Bt, int N, int K,
    u16* __restrict__ C, const float* __restrict__ bias,
    u16* __restrict__ qo, u16* __restrict__ ko, u16* __restrict__ vo,
    const float* __restrict__ bq, const float* __restrict__ bk,
    const float* __restrict__ bv)
{
    __shared__ __align__(16) u16 Asm[128 * 32];
    __shared__ __align__(16) u16 Bsm[BN * 32];
    const int tid  = threadIdx.x;
    const int lane = tid & 63;
    const int wave = tid >> 6;
    const int lrow = lane & 15, quad = lane >> 4;
    const int bm = blockIdx.x * 128, bn = blockIdx.y * BN;

    // staging: slot s covers row s>>2, kcols (s&3)*8..+7. LDS bytes = s*16.
    const int srow = tid >> 2;
    const int skol = (tid & 3) * 8;
    const u16* gA0 = A  + (size_t)(bm + srow) * K + skol;
    const u16* gA1 = gA0 + (size_t)64 * K;
    const u16* gB0 = Bt + (size_t)(bn + srow) * K + skol;
    const u16* gB1 = gB0 + (size_t)64 * K;   // used only when BN==128

    // wave -> 64 x (BN/2) output sub-tile
    const int wm = wave >> 1, wn = wave & 1;
    const int NT = (BN == 128) ? 4 : 2;      // 16-col fragments per wave
    f32x4 acc[4][(BN == 128) ? 4 : 2] = {};

    for (int kt = 0; kt < K; kt += 32) {
        __syncthreads();   // previous iteration's LDS reads complete
        glds16(gA0 + kt, &Asm[(size_t)tid * 8]);
        glds16(gA1 + kt, &Asm[((size_t)tid + 256) * 8]);
        glds16(gB0 + kt, &Bsm[(size_t)tid * 8]);
        if (BN == 128) glds16(gB1 + kt, &Bsm[((size_t)tid + 256) * 8]);
        __syncthreads();   // drains vmcnt(0): tiles visible to all waves

        bf16x8 af[4], bfr[(BN == 128) ? 4 : 2];
        #pragma unroll
        for (int mt = 0; mt < 4; mt++)
            af[mt] = *(const bf16x8*)&Asm[(wm * 64 + mt * 16 + lrow) * 32 + quad * 8];
        #pragma unroll
        for (int nt = 0; nt < NT; nt++)
            bfr[nt] = *(const bf16x8*)&Bsm[(wn * (BN / 2) + nt * 16 + lrow) * 32 + quad * 8];
        #pragma unroll
        for (int mt = 0; mt < 4; mt++)
            #pragma unroll
            for (int nt = 0; nt < NT; nt++)
                acc[mt][nt] = __builtin_amdgcn_mfma_f32_16x16x32_bf16(
                    af[mt], bfr[nt], acc[mt][nt], 0, 0, 0);
    }

    // epilogue: C/D layout col = lane&15, row = quad*4 + reg
    #pragma unroll
    for (int nt = 0; nt < NT; nt++) {
        int col = bn + wn * (BN / 2) + nt * 16 + lrow;
        int mat = 0, hh = 0, dd = 0;
        float bval;
        if (EPI == 2) {
            mat  = col >> 10; int dcol = col & 1023;
            hh = dcol >> 6;   dd = dcol & 63;
            const float* bp = (mat == 0) ? bq : ((mat == 1) ? bk : bv);
            bval = bp[dcol];
        } else {
            bval = bias[col];
        }
        #pragma unroll
        for (int mt = 0; mt < 4; mt++) {
            #pragma unroll
            for (int r = 0; r < 4; r++) {
                int row = bm + wm * 64 + mt * 16 + quad * 4 + r;
                float v = acc[mt][nt][r] + bval;
                if (EPI == 1) v = 0.5f * v * (1.0f + erff(v * 0.70710678118654752f));
                if (EPI == 2) {
                    int b = row >> 9, s = row & 511;   // b = batch within group
                    u16* dst = (mat == 0) ? qo : ((mat == 1) ? ko : vo);
                    dst[(((size_t)(b * 16 + hh)) * 512 + s) * 64 + dd] = f2b(v);
                } else {
                    C[(size_t)row * N + col] = f2b(v);
                }
            }
        }
    }
}

// ---------------------------------------------------------------------------
// Flash attention: block = (qtile of 64, head, batch-in-group), 256 threads.
// q,k,v bf16 [8,16,512,64]; scores = q@k^T/8 + mask*-1e9 + adj(fp32);
// softmax; @v. ctx bf16 [4096,1024] (row = b_local*512 + qrow) for Wo GEMM.
// K tile staged via global_load_lds (linear layout); V transposed via regs.
// ---------------------------------------------------------------------------
__global__ __launch_bounds__(256) void attn_kernel(
    const u16* __restrict__ Q, const u16* __restrict__ Kb, const u16* __restrict__ Vb,
    const float* __restrict__ adj, const int* __restrict__ mask, u16* __restrict__ ctx)
{
    const int S = 512, H = 16;
    __shared__ __align__(16) u16 Ksm[32 * 64];      // [key][d]
    __shared__ __align__(16) u16 Vt [64 * 32];      // [d][key]
    __shared__ __align__(16) u16 Psm[4][16 * 32];   // per-wave P relayout buffer

    int tid = threadIdx.x, lane = tid & 63, wave = tid >> 6;
    int lrow = lane & 15, quad = lane >> 4;
    int qt = blockIdx.x, h = blockIdx.y, b = blockIdx.z;   // b = batch within group

    size_t headoff = ((size_t)(b * H + h)) * S * 64;
    const u16* qp = Q + headoff;
    const u16* kp = Kb + headoff;
    const u16* vp = Vb + headoff;
    const float* adjb = adj + (size_t)b * S * S;
    const int* maskb = mask + b * S;
    int q0 = qt * 64 + wave * 16;

    bf16x8 qf0 = *(const bf16x8*)(qp + (size_t)(q0 + lrow) * 64 + quad * 8);
    bf16x8 qf1 = *(const bf16x8*)(qp + (size_t)(q0 + lrow) * 64 + 32 + quad * 8);

    float m_run[4] = {-1e30f, -1e30f, -1e30f, -1e30f};
    float l_run[4] = {0.f, 0.f, 0.f, 0.f};
    f32x4 o[4] = {};

    int str = tid >> 3;          // 0..31  staging row (key)
    int stc = (tid & 7) * 8;     // 0..56  staging col (d)

    for (int kt = 0; kt < S; kt += 32) {
        __syncthreads();
        // K: LDS offset (str*64+stc)*2 == tid*16 bytes -> glds-compatible
        glds16(kp + (size_t)(kt + str) * 64 + stc, &Ksm[str * 64 + stc]);
        {
            bf16x8 vv = *(const bf16x8*)(vp + (size_t)(kt + str) * 64 + stc);
            const u16* tv = (const u16*)&vv;
            #pragma unroll
            for (int j = 0; j < 8; j++) Vt[(stc + j) * 32 + str] = tv[j];
        }
        __syncthreads();

        f32x4 sc[2];
        #pragma unroll
        for (int f = 0; f < 2; f++) {
            f32x4 cf = {};
            bf16x8 kf0 = *(const bf16x8*)&Ksm[(f * 16 + lrow) * 64 + quad * 8];
            bf16x8 kf1 = *(const bf16x8*)&Ksm[(f * 16 + lrow) * 64 + 32 + quad * 8];
            cf = __builtin_amdgcn_mfma_f32_16x16x32_bf16(qf0, kf0, cf, 0, 0, 0);
            cf = __builtin_amdgcn_mfma_f32_16x16x32_bf16(qf1, kf1, cf, 0, 0, 0);
            int key = kt + f * 16 + lrow;
            float mterm = maskb[key] ? -1e9f : 0.0f;
            #pragma unroll
            for (int r = 0; r < 4; r++) {
                int qrow = q0 + quad * 4 + r;
                sc[f][r] = cf[r] * 0.125f + mterm + adjb[(size_t)qrow * S + key];
            }
        }

        float mx[4], al[4], sm[4];
        #pragma unroll
        for (int r = 0; r < 4; r++) mx[r] = fmaxf(sc[0][r], sc[1][r]);
        #pragma unroll
        for (int mk = 1; mk < 16; mk <<= 1)
            #pragma unroll
            for (int r = 0; r < 4; r++) mx[r] = fmaxf(mx[r], __shfl_xor(mx[r], mk));
        #pragma unroll
        for (int r = 0; r < 4; r++) {
            float mn = fmaxf(m_run[r], mx[r]);
            al[r] = __expf(fminf(m_run[r] - mn, 0.f));
            m_run[r] = mn;
        }
        #pragma unroll
        for (int f = 0; f < 2; f++)
            #pragma unroll
            for (int r = 0; r < 4; r++)
                sc[f][r] = __expf(fminf(sc[f][r] - m_run[r], 0.f));
        #pragma unroll
        for (int r = 0; r < 4; r++) sm[r] = sc[0][r] + sc[1][r];
        #pragma unroll
        for (int mk = 1; mk < 16; mk <<= 1)
            #pragma unroll
            for (int r = 0; r < 4; r++) sm[r] += __shfl_xor(sm[r], mk);
        #pragma unroll
        for (int r = 0; r < 4; r++) l_run[r] = l_run[r] * al[r] + sm[r];
        #pragma unroll
        for (int nt = 0; nt < 4; nt++)
            #pragma unroll
            for (int r = 0; r < 4; r++) o[nt][r] *= al[r];

        #pragma unroll
        for (int f = 0; f < 2; f++)
            #pragma unroll
            for (int r = 0; r < 4; r++)
                Psm[wave][(quad * 4 + r) * 32 + f * 16 + lrow] = f2b(sc[f][r]);
        bf16x8 pa = *(const bf16x8*)&Psm[wave][lrow * 32 + quad * 8];
        #pragma unroll
        for (int nt = 0; nt < 4; nt++) {
            bf16x8 vf = *(const bf16x8*)&Vt[(nt * 16 + lrow) * 32 + quad * 8];
            o[nt] = __builtin_amdgcn_mfma_f32_16x16x32_bf16(pa, vf, o[nt], 0, 0, 0);
        }
    }

    // ctx[b_local*512 + qrow, h*64 + d]
    #pragma unroll
    for (int nt = 0; nt < 4; nt++)
        #pragma unroll
        for (int r = 0; r < 4; r++) {
            int qrow = q0 + quad * 4 + r;
            ctx[((size_t)b * 512 + qrow) * 1024 + h * 64 + nt * 16 + lrow] =
                f2b(o[nt][r] / l_run[r]);
        }
}

// ---------------------------------------------------------------------------
// out = LayerNorm(X + Y): mean over D=1024, unbiased std (ddof=1), /(std+1e-6)
// MODE 0: X fp32, Y bf16, out bf16   MODE 1: X bf16, Y bf16, out fp32
// ---------------------------------------------------------------------------
template<int MODE>
__global__ __launch_bounds__(256) void add_ln(
    const void* __restrict__ Xv, const void* __restrict__ Yv,
    const float* __restrict__ gamma, const float* __restrict__ beta,
    void* __restrict__ outv)
{
    const int D = 1024;
    int row = blockIdx.x, tid = threadIdx.x;
    int lane = tid & 63, wave = tid >> 6;
    size_t base = (size_t)row * D + tid * 4;

    float x[4];
    if (MODE == 0) {
        float4 xf = *(const float4*)((const float*)Xv + base);
        u16x4  uy = *(const u16x4*)((const u16*)Yv + base);
        x[0] = xf.x + b2f(uy[0]); x[1] = xf.y + b2f(uy[1]);
        x[2] = xf.z + b2f(uy[2]); x[3] = xf.w + b2f(uy[3]);
    } else {
        u16x4 ux = *(const u16x4*)((const u16*)Xv + base);
        u16x4 uy = *(const u16x4*)((const u16*)Yv + base);
        #pragma unroll
        for (int j = 0; j < 4; j++) x[j] = b2f(ux[j]) + b2f(uy[j]);
    }

    float s = x[0] + x[1] + x[2] + x[3];
    #pragma unroll
    for (int mk = 1; mk < 64; mk <<= 1) s += __shfl_xor(s, mk);
    __shared__ float red[8];
    if (lane == 0) red[wave] = s;
    __syncthreads();
    float mean = (red[0] + red[1] + red[2] + red[3]) * (1.0f / 1024.0f);

    float c[4], q = 0.f;
    #pragma unroll
    for (int j = 0; j < 4; j++) { c[j] = x[j] - mean; q += c[j] * c[j]; }
    #pragma unroll
    for (int mk = 1; mk < 64; mk <<= 1) q += __shfl_xor(q, mk);
    if (lane == 0) red[4 + wave] = q;
    __syncthreads();
    float var = (red[4] + red[5] + red[6] + red[7]) * (1.0f / 1023.0f);
    float inv = 1.0f / (sqrtf(var) + 1e-6f);

    float4 g4 = *(const float4*)(gamma + tid * 4);
    float4 b4 = *(const float4*)(beta + tid * 4);
    float gv[4] = {g4.x, g4.y, g4.z, g4.w};
    float bv[4] = {b4.x, b4.y, b4.z, b4.w};
    if (MODE == 0) {
        u16x4 ov;
        #pragma unroll
        for (int j = 0; j < 4; j++) ov[j] = f2b(gv[j] * c[j] * inv + bv[j]);
        *(u16x4*)((u16*)outv + base) = ov;
    } else {
        float4 ov;
        ov.x = gv[0] * c[0] * inv + bv[0];
        ov.y = gv[1] * c[1] * inv + bv[1];
        ov.z = gv[2] * c[2] * inv + bv[2];
        ov.w = gv[3] * c[3] * inv + bv[3];
        *(float4*)((float*)outv + base) = ov;
    }
}

// ---------------------------------------------------------------------------
// Workspace (bf16 unless noted), 96 MB peak:
//   [ 0, 6) Wqkv_t  [ 6, 8) Wo_t  [ 8,16) W1_t  [16,24) W2_t
//   [24,56) out1 (16384x1024)
//   attn phase (per 8-batch group): [56,64) q [64,72) k [72,80) v
//     [80,88) ctx [88,96) x_bf16 (QKV A operand), then overwritten by attn_out
//   FFN phase (per 4096-row chunk): [56,88) hidden [88,96) ffn
// ---------------------------------------------------------------------------
extern "C" void kernel_launch(void* const* d_in, const int* in_sizes, int n_in,
                              void* d_out, int out_size, void* d_ws, size_t ws_size,
                              hipStream_t stream)
{
    const float* x    = (const float*)d_in[0];
    const int*   mask = (const int*)d_in[1];
    const float* adj  = (const float*)d_in[2];
    const float* Wq = (const float*)d_in[4];  const float* bq = (const float*)d_in[5];
    const float* Wk = (const float*)d_in[6];  const float* bk = (const float*)d_in[7];
    const float* Wv = (const float*)d_in[8];  const float* bv = (const float*)d_in[9];
    const float* Wo = (const float*)d_in[10]; const float* bo = (const float*)d_in[11];
    const float* W1 = (const float*)d_in[12]; const float* b1 = (const float*)d_in[13];
    const float* W2 = (const float*)d_in[14]; const float* b2 = (const float*)d_in[15];
    const float* gamma = (const float*)d_in[16];
    const float* beta  = (const float*)d_in[17];
    float* out = (float*)d_out;

    const size_t MB = 1024ull * 1024;
    char* w = (char*)d_ws;
    u16* Wqkv_t = (u16*)(w + 0 * MB);
    u16* Wo_t   = (u16*)(w + 6 * MB);
    u16* W1_t   = (u16*)(w + 8 * MB);
    u16* W2_t   = (u16*)(w + 16 * MB);
    u16* out1   = (u16*)(w + 24 * MB);
    u16* qg     = (u16*)(w + 56 * MB);
    u16* kg     = (u16*)(w + 64 * MB);
    u16* vg     = (u16*)(w + 72 * MB);
    u16* ctxg   = (u16*)(w + 80 * MB);
    u16* aog    = (u16*)(w + 88 * MB);   // x_bf16 during QKV, attn_out after Wo
    u16* hid    = (u16*)(w + 56 * MB);   // overlays q/k/v/ctx (dead in FFN phase)
    u16* ffn    = (u16*)(w + 88 * MB);   // overlays attn_out

    dim3 tb(32, 8);
    transpose_f32_bf16<<<dim3(32, 32),  tb, 0, stream>>>(Wq, Wqkv_t,                1024, 1024);
    transpose_f32_bf16<<<dim3(32, 32),  tb, 0, stream>>>(Wk, Wqkv_t + 1024ull*1024, 1024, 1024);
    transpose_f32_bf16<<<dim3(32, 32),  tb, 0, stream>>>(Wv, Wqkv_t + 2048ull*1024, 1024, 1024);
    transpose_f32_bf16<<<dim3(32, 32),  tb, 0, stream>>>(Wo, Wo_t,                  1024, 1024);
    transpose_f32_bf16<<<dim3(128, 32), tb, 0, stream>>>(W1, W1_t,                  1024, 4096);
    transpose_f32_bf16<<<dim3(32, 128), tb, 0, stream>>>(W2, W2_t,                  4096, 1024);

    // ---- attention phase: 4 groups of 8 batches (4096 rows each) ----
    for (int g = 0; g < 4; g++) {
        const float* xg = x + (size_t)g * 4096 * 1024;
        // x chunk -> bf16 (into aog region; dead until Wo writes it)
        cvt_f32_bf16<<<2048, 256, 0, stream>>>(xg, aog);
        gemm_bt<2, 128><<<dim3(32, 24), 256, 0, stream>>>(aog, Wqkv_t, 3072, 1024,
            nullptr, nullptr, qg, kg, vg, bq, bk, bv);
        attn_kernel<<<dim3(8, 16, 8), 256, 0, stream>>>(qg, kg, vg,
            adj + (size_t)g * 8 * 512 * 512, mask + g * 8 * 512, ctxg);
        gemm_bt<0, 64><<<dim3(32, 16), 256, 0, stream>>>(ctxg, Wo_t, 1024, 1024,
            aog, bo, nullptr, nullptr, nullptr, nullptr, nullptr, nullptr);
        add_ln<0><<<4096, 256, 0, stream>>>(xg, aog, gamma, beta,
            out1 + (size_t)g * 4096 * 1024);
    }

    // ---- FFN phase: 4 row chunks of 4096 ----
    for (int c = 0; c < 4; c++) {
        const u16* o1c = out1 + (size_t)c * 4096 * 1024;
        gemm_bt<1, 128><<<dim3(32, 32), 256, 0, stream>>>(o1c, W1_t, 4096, 1024,
            hid, b1, nullptr, nullptr, nullptr, nullptr, nullptr, nullptr);
        gemm_bt<0, 64><<<dim3(32, 16), 256, 0, stream>>>(hid, W2_t, 1024, 4096,
            ffn, b2, nullptr, nullptr, nullptr, nullptr, nullptr, nullptr);
        add_ln<1><<<4096, 256, 0, stream>>>(o1c, ffn, gamma, beta,
            out + (size_t)c * 4096 * 1024);
    }
}

// Round 3
// 1273.859 us; speedup vs baseline: 1.0369x; 1.0369x over previous
//
#include <hip/hip_runtime.h>
#include <stdint.h>
#include <math.h>

typedef unsigned short u16;
typedef __attribute__((ext_vector_type(8))) __bf16 bf16x8;
typedef __attribute__((ext_vector_type(4))) float f32x4;
typedef __attribute__((ext_vector_type(4))) unsigned short u16x4;

__device__ __forceinline__ float b2f(u16 u) {
    unsigned int i = ((unsigned int)u) << 16;
    float f; __builtin_memcpy(&f, &i, 4); return f;
}
__device__ __forceinline__ u16 f2b(float f) {
    unsigned int i; __builtin_memcpy(&i, &f, 4);
    i = (i + 0x7FFFu + ((i >> 16) & 1u)) >> 16;   // RNE
    return (u16)i;
}
// load 8 consecutive fp32, convert to bf16x8 (RNE)
__device__ __forceinline__ bf16x8 ld8_cvt(const float* p) {
    float4 f0 = *(const float4*)p, f1 = *(const float4*)(p + 4);
    u16 t[8] = {f2b(f0.x), f2b(f0.y), f2b(f0.z), f2b(f0.w),
                f2b(f1.x), f2b(f1.y), f2b(f1.z), f2b(f1.w)};
    bf16x8 r; __builtin_memcpy(&r, t, 16); return r;
}

// async global->LDS 16B copy (global_load_lds_dwordx4). LDS dest must be
// wave-uniform base + lane*16 — all call sites below satisfy this (offset
// is tid*16 bytes within a 256-thread block => per-wave base + lane*16).
__device__ __forceinline__ void glds16(const u16* g, u16* l) {
    __builtin_amdgcn_global_load_lds(
        (const __attribute__((address_space(1))) void*)g,
        (__attribute__((address_space(3))) void*)l, 16, 0, 0);
}

// ---------------------------------------------------------------------------
// Transpose + fp32->bf16 convert: in[R][C] fp32 -> out[C][R] bf16.
// block (32,8), grid (C/32, R/32)
// ---------------------------------------------------------------------------
__global__ __launch_bounds__(256) void transpose_f32_bf16(
    const float* __restrict__ in, u16* __restrict__ out, int R, int C)
{
    __shared__ float t[32][33];
    int bx = blockIdx.x * 32, by = blockIdx.y * 32;
    int x = threadIdx.x, y = threadIdx.y;
    #pragma unroll
    for (int j = 0; j < 32; j += 8)
        t[y + j][x] = in[(size_t)(by + y + j) * C + bx + x];
    __syncthreads();
    #pragma unroll
    for (int j = 0; j < 32; j += 8)
        out[(size_t)(bx + y + j) * R + by + x] = f2b(t[x][y + j]);
}

// ---------------------------------------------------------------------------
// Elementwise fp32 -> bf16 convert (for x before the QKV GEMM).
// ---------------------------------------------------------------------------
__global__ __launch_bounds__(256) void cvt_f32_bf16(
    const float* __restrict__ in, u16* __restrict__ out)
{
    size_t i = ((size_t)blockIdx.x * 256 + threadIdx.x) * 8;
    *(bf16x8*)(out + i) = ld8_cvt(in + i);
}

// ---------------------------------------------------------------------------
// GEMM: C[M,N] = A[M,K] @ Bt[N,K]^T (+bias, epilogue).  A,Bt bf16; acc fp32.
// EPI 0: C = acc + bias (bf16 out)   EPI 1: C = gelu_erf(acc + bias) (bf16)
// EPI 2: QKV permuted store into q/k/v [8,16,512,64] bf16 with per-matrix bias
// BM=128 x BN(template 128|64) tile, BK=32, 256 threads.
// 2-phase pipeline (T3-minimum): double-buffered LDS; stage(t+1) issued
// BEFORE compute(t); single __syncthreads per K-step drains vmcnt AFTER the
// MFMAs, so global latency overlaps ds_read+MFMA of the current tile.
// XCD-aware swizzle (T1): work-id = (phys%8)*(nwg/8)+phys/8 (all grids %8==0)
// ---------------------------------------------------------------------------
template<int EPI, int BN>
__global__ __launch_bounds__(256) void gemm_bt(
    const u16* __restrict__ A, const u16* __restrict__ Bt, int N, int K,
    u16* __restrict__ C, const float* __restrict__ bias,
    u16* __restrict__ qo, u16* __restrict__ ko, u16* __restrict__ vo,
    const float* __restrict__ bq, const float* __restrict__ bk,
    const float* __restrict__ bv)
{
    __shared__ __align__(16) u16 Asm[2][128 * 32];
    __shared__ __align__(16) u16 Bsm[2][BN * 32];
    const int tid  = threadIdx.x;
    const int lane = tid & 63;
    const int wave = tid >> 6;
    const int lrow = lane & 15, quad = lane >> 4;

    // XCD swizzle: consecutive work-ids (=> contiguous B bands) per XCD L2
    const int gx = gridDim.x;
    const int nwg = gx * gridDim.y;
    const int orig = blockIdx.y * gx + blockIdx.x;
    const int wg = (orig & 7) * (nwg >> 3) + (orig >> 3);
    const int bm = (wg % gx) * 128, bn = (wg / gx) * BN;

    // staging: slot s covers row s>>2, kcols (s&3)*8..+7. LDS bytes = s*16.
    const int srow = tid >> 2;
    const int skol = (tid & 3) * 8;
    const u16* gA0 = A  + (size_t)(bm + srow) * K + skol;
    const u16* gA1 = gA0 + (size_t)64 * K;
    const u16* gB0 = Bt + (size_t)(bn + srow) * K + skol;
    const u16* gB1 = gB0 + (size_t)64 * K;   // used only when BN==128

    // wave -> 64 x (BN/2) output sub-tile
    const int wm = wave >> 1, wn = wave & 1;
    constexpr int NT = (BN == 128) ? 4 : 2;  // 16-col fragments per wave
    f32x4 acc[4][NT] = {};

    // prologue: stage tile 0 into buffer 0
    glds16(gA0, &Asm[0][(size_t)tid * 8]);
    glds16(gA1, &Asm[0][((size_t)tid + 256) * 8]);
    glds16(gB0, &Bsm[0][(size_t)tid * 8]);
    if (BN == 128) glds16(gB1, &Bsm[0][((size_t)tid + 256) * 8]);
    __syncthreads();   // drains vmcnt(0): tile 0 resident

    int cur = 0;
    for (int kt = 0; kt < K; kt += 32) {
        const int nxt = kt + 32;
        if (nxt < K) {   // issue next-tile loads FIRST (latency overlaps MFMA)
            glds16(gA0 + nxt, &Asm[cur ^ 1][(size_t)tid * 8]);
            glds16(gA1 + nxt, &Asm[cur ^ 1][((size_t)tid + 256) * 8]);
            glds16(gB0 + nxt, &Bsm[cur ^ 1][(size_t)tid * 8]);
            if (BN == 128) glds16(gB1 + nxt, &Bsm[cur ^ 1][((size_t)tid + 256) * 8]);
        }

        bf16x8 af[4], bfr[NT];
        #pragma unroll
        for (int mt = 0; mt < 4; mt++)
            af[mt] = *(const bf16x8*)&Asm[cur][(wm * 64 + mt * 16 + lrow) * 32 + quad * 8];
        #pragma unroll
        for (int nt = 0; nt < NT; nt++)
            bfr[nt] = *(const bf16x8*)&Bsm[cur][(wn * (BN / 2) + nt * 16 + lrow) * 32 + quad * 8];
        #pragma unroll
        for (int mt = 0; mt < 4; mt++)
            #pragma unroll
            for (int nt = 0; nt < NT; nt++)
                acc[mt][nt] = __builtin_amdgcn_mfma_f32_16x16x32_bf16(
                    af[mt], bfr[nt], acc[mt][nt], 0, 0, 0);

        __syncthreads();   // drains vmcnt(0) for stage(t+1); protects buffers
        cur ^= 1;
    }

    // epilogue: C/D layout col = lane&15, row = quad*4 + reg
    #pragma unroll
    for (int nt = 0; nt < NT; nt++) {
        int col = bn + wn * (BN / 2) + nt * 16 + lrow;
        int mat = 0, hh = 0, dd = 0;
        float bval;
        if (EPI == 2) {
            mat  = col >> 10; int dcol = col & 1023;
            hh = dcol >> 6;   dd = dcol & 63;
            const float* bp = (mat == 0) ? bq : ((mat == 1) ? bk : bv);
            bval = bp[dcol];
        } else {
            bval = bias[col];
        }
        #pragma unroll
        for (int mt = 0; mt < 4; mt++) {
            #pragma unroll
            for (int r = 0; r < 4; r++) {
                int row = bm + wm * 64 + mt * 16 + quad * 4 + r;
                float v = acc[mt][nt][r] + bval;
                if (EPI == 1) v = 0.5f * v * (1.0f + erff(v * 0.70710678118654752f));
                if (EPI == 2) {
                    int b = row >> 9, s = row & 511;   // b = batch within group
                    u16* dst = (mat == 0) ? qo : ((mat == 1) ? ko : vo);
                    dst[(((size_t)(b * 16 + hh)) * 512 + s) * 64 + dd] = f2b(v);
                } else {
                    C[(size_t)row * N + col] = f2b(v);
                }
            }
        }
    }
}

// ---------------------------------------------------------------------------
// Flash attention: 256 threads/block; q,k,v bf16 [8,16,512,64].
// scores = q@k^T/8 + mask*-1e9 + adj(fp32); softmax; @v.
// 2-phase pipeline: K double-buffered via glds; V reg-staged (issue-early /
// ds_write-late, T14); adj prefetched to regs; ONE barrier per KV-tile
// (between softmax and PV — covers all cross-wave hazards).
// XCD swizzle: batch-in-group b pinned to one XCD (2MB K/V + 1MB adj in L2).
// ---------------------------------------------------------------------------
__global__ __launch_bounds__(256) void attn_kernel(
    const u16* __restrict__ Q, const u16* __restrict__ Kb, const u16* __restrict__ Vb,
    const float* __restrict__ adj, const int* __restrict__ mask, u16* __restrict__ ctx)
{
    const int S = 512, H = 16;
    __shared__ __align__(16) u16 Ksm[2][32 * 64];   // [key][d]
    __shared__ __align__(16) u16 Vt [2][64 * 32];   // [d][key]
    __shared__ __align__(16) u16 Psm[4][16 * 32];   // per-wave P relayout buffer

    int tid = threadIdx.x, lane = tid & 63, wave = tid >> 6;
    int lrow = lane & 15, quad = lane >> 4;

    // work swizzle: orig%8 -> b, so each XCD owns one batch's K/V/adj
    int orig = (blockIdx.z * 16 + blockIdx.y) * 8 + blockIdx.x;
    int b  = orig & 7;
    int h  = (orig >> 3) & 15;
    int qt = orig >> 7;

    size_t headoff = ((size_t)(b * H + h)) * S * 64;
    const u16* qp = Q + headoff;
    const u16* kp = Kb + headoff;
    const u16* vp = Vb + headoff;
    const float* adjb = adj + (size_t)b * S * S;
    const int* maskb = mask + b * S;
    int q0 = qt * 64 + wave * 16;

    bf16x8 qf0 = *(const bf16x8*)(qp + (size_t)(q0 + lrow) * 64 + quad * 8);
    bf16x8 qf1 = *(const bf16x8*)(qp + (size_t)(q0 + lrow) * 64 + 32 + quad * 8);

    float m_run[4] = {-1e30f, -1e30f, -1e30f, -1e30f};
    float l_run[4] = {0.f, 0.f, 0.f, 0.f};
    f32x4 o[4] = {};

    int str = tid >> 3;          // 0..31  staging row (key)
    int stc = (tid & 7) * 8;     // 0..56  staging col (d)

    // prologue: stage K tile 0 (glds) + V tile 0 (regs)
    glds16(kp + (size_t)str * 64 + stc, &Ksm[0][str * 64 + stc]);
    bf16x8 vcur = *(const bf16x8*)(vp + (size_t)str * 64 + stc);
    __syncthreads();   // K tile 0 resident

    int cur = 0;
    for (int kt = 0; kt < S; kt += 32) {
        const int nxt = kt + 32;
        bf16x8 vnxt;
        if (nxt < S) {   // issue next K (glds) + next V (regs) first
            glds16(kp + (size_t)(nxt + str) * 64 + stc, &Ksm[cur ^ 1][str * 64 + stc]);
            vnxt = *(const bf16x8*)(vp + (size_t)(nxt + str) * 64 + stc);
        }
        // write CURRENT V tile (regs, loaded last iter) into Vt[cur]
        {
            const u16* tv = (const u16*)&vcur;
            #pragma unroll
            for (int j = 0; j < 8; j++) Vt[cur][(stc + j) * 32 + str] = tv[j];
        }
        // adj prefetch for current tile (hidden under QK^T)
        float adjv[2][4];
        #pragma unroll
        for (int f = 0; f < 2; f++)
            #pragma unroll
            for (int r = 0; r < 4; r++)
                adjv[f][r] = adjb[(size_t)(q0 + quad * 4 + r) * S + kt + f * 16 + lrow];

        f32x4 sc[2];
        #pragma unroll
        for (int f = 0; f < 2; f++) {
            f32x4 cf = {};
            bf16x8 kf0 = *(const bf16x8*)&Ksm[cur][(f * 16 + lrow) * 64 + quad * 8];
            bf16x8 kf1 = *(const bf16x8*)&Ksm[cur][(f * 16 + lrow) * 64 + 32 + quad * 8];
            cf = __builtin_amdgcn_mfma_f32_16x16x32_bf16(qf0, kf0, cf, 0, 0, 0);
            cf = __builtin_amdgcn_mfma_f32_16x16x32_bf16(qf1, kf1, cf, 0, 0, 0);
            int key = kt + f * 16 + lrow;
            float mterm = maskb[key] ? -1e9f : 0.0f;
            #pragma unroll
            for (int r = 0; r < 4; r++)
                sc[f][r] = cf[r] * 0.125f + mterm + adjv[f][r];
        }

        float mx[4], al[4], sm[4];
        #pragma unroll
        for (int r = 0; r < 4; r++) mx[r] = fmaxf(sc[0][r], sc[1][r]);
        #pragma unroll
        for (int mk = 1; mk < 16; mk <<= 1)
            #pragma unroll
            for (int r = 0; r < 4; r++) mx[r] = fmaxf(mx[r], __shfl_xor(mx[r], mk));
        #pragma unroll
        for (int r = 0; r < 4; r++) {
            float mn = fmaxf(m_run[r], mx[r]);
            al[r] = __expf(fminf(m_run[r] - mn, 0.f));
            m_run[r] = mn;
        }
        #pragma unroll
        for (int f = 0; f < 2; f++)
            #pragma unroll
            for (int r = 0; r < 4; r++)
                sc[f][r] = __expf(fminf(sc[f][r] - m_run[r], 0.f));
        #pragma unroll
        for (int r = 0; r < 4; r++) sm[r] = sc[0][r] + sc[1][r];
        #pragma unroll
        for (int mk = 1; mk < 16; mk <<= 1)
            #pragma unroll
            for (int r = 0; r < 4; r++) sm[r] += __shfl_xor(sm[r], mk);
        #pragma unroll
        for (int r = 0; r < 4; r++) l_run[r] = l_run[r] * al[r] + sm[r];
        #pragma unroll
        for (int nt = 0; nt < 4; nt++)
            #pragma unroll
            for (int r = 0; r < 4; r++) o[nt][r] *= al[r];

        #pragma unroll
        for (int f = 0; f < 2; f++)
            #pragma unroll
            for (int r = 0; r < 4; r++)
                Psm[wave][(quad * 4 + r) * 32 + f * 16 + lrow] = f2b(sc[f][r]);
        bf16x8 pa = *(const bf16x8*)&Psm[wave][lrow * 32 + quad * 8];

        __syncthreads();   // ONE barrier: Vt[cur] visible to all waves,
                           // K(nxt) glds drained (vmcnt 0), K(cur) reads done
        #pragma unroll
        for (int nt = 0; nt < 4; nt++) {
            bf16x8 vf = *(const bf16x8*)&Vt[cur][(nt * 16 + lrow) * 32 + quad * 8];
            o[nt] = __builtin_amdgcn_mfma_f32_16x16x32_bf16(pa, vf, o[nt], 0, 0, 0);
        }
        if (nxt < S) vcur = vnxt;
        cur ^= 1;
    }

    // ctx[b_local*512 + qrow, h*64 + d]
    #pragma unroll
    for (int nt = 0; nt < 4; nt++)
        #pragma unroll
        for (int r = 0; r < 4; r++) {
            int qrow = q0 + quad * 4 + r;
            ctx[((size_t)b * 512 + qrow) * 1024 + h * 64 + nt * 16 + lrow] =
                f2b(o[nt][r] / l_run[r]);
        }
}

// ---------------------------------------------------------------------------
// out = LayerNorm(X + Y): mean over D=1024, unbiased std (ddof=1), /(std+1e-6)
// MODE 0: X fp32, Y bf16, out bf16   MODE 1: X bf16, Y bf16, out fp32
// ---------------------------------------------------------------------------
template<int MODE>
__global__ __launch_bounds__(256) void add_ln(
    const void* __restrict__ Xv, const void* __restrict__ Yv,
    const float* __restrict__ gamma, const float* __restrict__ beta,
    void* __restrict__ outv)
{
    const int D = 1024;
    int row = blockIdx.x, tid = threadIdx.x;
    int lane = tid & 63, wave = tid >> 6;
    size_t base = (size_t)row * D + tid * 4;

    float x[4];
    if (MODE == 0) {
        float4 xf = *(const float4*)((const float*)Xv + base);
        u16x4  uy = *(const u16x4*)((const u16*)Yv + base);
        x[0] = xf.x + b2f(uy[0]); x[1] = xf.y + b2f(uy[1]);
        x[2] = xf.z + b2f(uy[2]); x[3] = xf.w + b2f(uy[3]);
    } else {
        u16x4 ux = *(const u16x4*)((const u16*)Xv + base);
        u16x4 uy = *(const u16x4*)((const u16*)Yv + base);
        #pragma unroll
        for (int j = 0; j < 4; j++) x[j] = b2f(ux[j]) + b2f(uy[j]);
    }

    float s = x[0] + x[1] + x[2] + x[3];
    #pragma unroll
    for (int mk = 1; mk < 64; mk <<= 1) s += __shfl_xor(s, mk);
    __shared__ float red[8];
    if (lane == 0) red[wave] = s;
    __syncthreads();
    float mean = (red[0] + red[1] + red[2] + red[3]) * (1.0f / 1024.0f);

    float c[4], q = 0.f;
    #pragma unroll
    for (int j = 0; j < 4; j++) { c[j] = x[j] - mean; q += c[j] * c[j]; }
    #pragma unroll
    for (int mk = 1; mk < 64; mk <<= 1) q += __shfl_xor(q, mk);
    if (lane == 0) red[4 + wave] = q;
    __syncthreads();
    float var = (red[4] + red[5] + red[6] + red[7]) * (1.0f / 1023.0f);
    float inv = 1.0f / (sqrtf(var) + 1e-6f);

    float4 g4 = *(const float4*)(gamma + tid * 4);
    float4 b4 = *(const float4*)(beta + tid * 4);
    float gv[4] = {g4.x, g4.y, g4.z, g4.w};
    float bv[4] = {b4.x, b4.y, b4.z, b4.w};
    if (MODE == 0) {
        u16x4 ov;
        #pragma unroll
        for (int j = 0; j < 4; j++) ov[j] = f2b(gv[j] * c[j] * inv + bv[j]);
        *(u16x4*)((u16*)outv + base) = ov;
    } else {
        float4 ov;
        ov.x = gv[0] * c[0] * inv + bv[0];
        ov.y = gv[1] * c[1] * inv + bv[1];
        ov.z = gv[2] * c[2] * inv + bv[2];
        ov.w = gv[3] * c[3] * inv + bv[3];
        *(float4*)((float*)outv + base) = ov;
    }
}

// ---------------------------------------------------------------------------
// Workspace (bf16 unless noted), 96 MB peak:
//   [ 0, 6) Wqkv_t  [ 6, 8) Wo_t  [ 8,16) W1_t  [16,24) W2_t
//   [24,56) out1 (16384x1024)
//   attn phase (per 8-batch group): [56,64) q [64,72) k [72,80) v
//     [80,88) ctx [88,96) x_bf16 (QKV A operand), then overwritten by attn_out
//   FFN phase (per 4096-row chunk): [56,88) hidden [88,96) ffn
// ---------------------------------------------------------------------------
extern "C" void kernel_launch(void* const* d_in, const int* in_sizes, int n_in,
                              void* d_out, int out_size, void* d_ws, size_t ws_size,
                              hipStream_t stream)
{
    const float* x    = (const float*)d_in[0];
    const int*   mask = (const int*)d_in[1];
    const float* adj  = (const float*)d_in[2];
    const float* Wq = (const float*)d_in[4];  const float* bq = (const float*)d_in[5];
    const float* Wk = (const float*)d_in[6];  const float* bk = (const float*)d_in[7];
    const float* Wv = (const float*)d_in[8];  const float* bv = (const float*)d_in[9];
    const float* Wo = (const float*)d_in[10]; const float* bo = (const float*)d_in[11];
    const float* W1 = (const float*)d_in[12]; const float* b1 = (const float*)d_in[13];
    const float* W2 = (const float*)d_in[14]; const float* b2 = (const float*)d_in[15];
    const float* gamma = (const float*)d_in[16];
    const float* beta  = (const float*)d_in[17];
    float* out = (float*)d_out;

    const size_t MB = 1024ull * 1024;
    char* w = (char*)d_ws;
    u16* Wqkv_t = (u16*)(w + 0 * MB);
    u16* Wo_t   = (u16*)(w + 6 * MB);
    u16* W1_t   = (u16*)(w + 8 * MB);
    u16* W2_t   = (u16*)(w + 16 * MB);
    u16* out1   = (u16*)(w + 24 * MB);
    u16* qg     = (u16*)(w + 56 * MB);
    u16* kg     = (u16*)(w + 64 * MB);
    u16* vg     = (u16*)(w + 72 * MB);
    u16* ctxg   = (u16*)(w + 80 * MB);
    u16* aog    = (u16*)(w + 88 * MB);   // x_bf16 during QKV, attn_out after Wo
    u16* hid    = (u16*)(w + 56 * MB);   // overlays q/k/v/ctx (dead in FFN phase)
    u16* ffn    = (u16*)(w + 88 * MB);   // overlays attn_out

    dim3 tb(32, 8);
    transpose_f32_bf16<<<dim3(32, 32),  tb, 0, stream>>>(Wq, Wqkv_t,                1024, 1024);
    transpose_f32_bf16<<<dim3(32, 32),  tb, 0, stream>>>(Wk, Wqkv_t + 1024ull*1024, 1024, 1024);
    transpose_f32_bf16<<<dim3(32, 32),  tb, 0, stream>>>(Wv, Wqkv_t + 2048ull*1024, 1024, 1024);
    transpose_f32_bf16<<<dim3(32, 32),  tb, 0, stream>>>(Wo, Wo_t,                  1024, 1024);
    transpose_f32_bf16<<<dim3(128, 32), tb, 0, stream>>>(W1, W1_t,                  1024, 4096);
    transpose_f32_bf16<<<dim3(32, 128), tb, 0, stream>>>(W2, W2_t,                  4096, 1024);

    // ---- attention phase: 4 groups of 8 batches (4096 rows each) ----
    for (int g = 0; g < 4; g++) {
        const float* xg = x + (size_t)g * 4096 * 1024;
        // x chunk -> bf16 (into aog region; dead until Wo writes it)
        cvt_f32_bf16<<<2048, 256, 0, stream>>>(xg, aog);
        gemm_bt<2, 128><<<dim3(32, 24), 256, 0, stream>>>(aog, Wqkv_t, 3072, 1024,
            nullptr, nullptr, qg, kg, vg, bq, bk, bv);
        attn_kernel<<<dim3(8, 16, 8), 256, 0, stream>>>(qg, kg, vg,
            adj + (size_t)g * 8 * 512 * 512, mask + g * 8 * 512, ctxg);
        gemm_bt<0, 64><<<dim3(32, 16), 256, 0, stream>>>(ctxg, Wo_t, 1024, 1024,
            aog, bo, nullptr, nullptr, nullptr, nullptr, nullptr, nullptr);
        add_ln<0><<<4096, 256, 0, stream>>>(xg, aog, gamma, beta,
            out1 + (size_t)g * 4096 * 1024);
    }

    // ---- FFN phase: 4 row chunks of 4096 ----
    for (int c = 0; c < 4; c++) {
        const u16* o1c = out1 + (size_t)c * 4096 * 1024;
        gemm_bt<1, 128><<<dim3(32, 32), 256, 0, stream>>>(o1c, W1_t, 4096, 1024,
            hid, b1, nullptr, nullptr, nullptr, nullptr, nullptr, nullptr);
        gemm_bt<0, 64><<<dim3(32, 16), 256, 0, stream>>>(hid, W2_t, 1024, 4096,
            ffn, b2, nullptr, nullptr, nullptr, nullptr, nullptr, nullptr);
        add_ln<1><<<4096, 256, 0, stream>>>(o1c, ffn, gamma, beta,
            out + (size_t)c * 4096 * 1024);
    }
}

// Round 4
// 1252.769 us; speedup vs baseline: 1.0544x; 1.0168x over previous
//
#include <hip/hip_runtime.h>
#include <stdint.h>
#include <math.h>

typedef unsigned short u16;
typedef __attribute__((ext_vector_type(8))) __bf16 bf16x8;
typedef __attribute__((ext_vector_type(4))) float f32x4;
typedef __attribute__((ext_vector_type(4))) unsigned short u16x4;

__device__ __forceinline__ float b2f(u16 u) {
    unsigned int i = ((unsigned int)u) << 16;
    float f; __builtin_memcpy(&f, &i, 4); return f;
}
__device__ __forceinline__ u16 f2b(float f) {
    unsigned int i; __builtin_memcpy(&i, &f, 4);
    i = (i + 0x7FFFu + ((i >> 16) & 1u)) >> 16;   // RNE
    return (u16)i;
}
// load 8 consecutive fp32, convert to bf16x8 (RNE)
__device__ __forceinline__ bf16x8 ld8_cvt(const float* p) {
    float4 f0 = *(const float4*)p, f1 = *(const float4*)(p + 4);
    u16 t[8] = {f2b(f0.x), f2b(f0.y), f2b(f0.z), f2b(f0.w),
                f2b(f1.x), f2b(f1.y), f2b(f1.z), f2b(f1.w)};
    bf16x8 r; __builtin_memcpy(&r, t, 16); return r;
}

// async global->LDS 16B copy (global_load_lds_dwordx4). LDS dest must be
// wave-uniform base + lane*16 — all call sites below satisfy this (offset
// is tid*16 bytes within a 256-thread block => per-wave base + lane*16).
__device__ __forceinline__ void glds16(const u16* g, u16* l) {
    __builtin_amdgcn_global_load_lds(
        (const __attribute__((address_space(1))) void*)g,
        (__attribute__((address_space(3))) void*)l, 16, 0, 0);
}

// ---------------------------------------------------------------------------
// Transpose + fp32->bf16 convert: in[R][C] fp32 -> out[C][R] bf16.
// block (32,8), grid (C/32, R/32)
// ---------------------------------------------------------------------------
__global__ __launch_bounds__(256) void transpose_f32_bf16(
    const float* __restrict__ in, u16* __restrict__ out, int R, int C)
{
    __shared__ float t[32][33];
    int bx = blockIdx.x * 32, by = blockIdx.y * 32;
    int x = threadIdx.x, y = threadIdx.y;
    #pragma unroll
    for (int j = 0; j < 32; j += 8)
        t[y + j][x] = in[(size_t)(by + y + j) * C + bx + x];
    __syncthreads();
    #pragma unroll
    for (int j = 0; j < 32; j += 8)
        out[(size_t)(bx + y + j) * R + by + x] = f2b(t[x][y + j]);
}

// ---------------------------------------------------------------------------
// Elementwise fp32 -> bf16 convert (for x before the QKV GEMM).
// ---------------------------------------------------------------------------
__global__ __launch_bounds__(256) void cvt_f32_bf16(
    const float* __restrict__ in, u16* __restrict__ out)
{
    size_t i = ((size_t)blockIdx.x * 256 + threadIdx.x) * 8;
    *(bf16x8*)(out + i) = ld8_cvt(in + i);
}

// ---------------------------------------------------------------------------
// GEMM: C[M,N] = A[M,K] @ Bt[N,K]^T (+bias, epilogue).  A,Bt bf16; acc fp32.
// EPI 0: C = acc + bias (bf16 out)   EPI 1: C = gelu_erf(acc + bias) (bf16)
// EPI 2: QKV permuted store into q/k/v [8,16,512,64] bf16 with per-matrix bias
// BM=128 x BN(template 128|64) tile, BK=32, 256 threads.
// T4 counted-vmcnt double-buffer: raw s_barrier + s_waitcnt vmcnt(L) so the
// next tile's global_load_lds ops stay IN FLIGHT across the barrier (AITER
// pattern — never drain to 0 in the main loop; single vmcnt(0) at last iter).
// Hazards: vmcnt retires in issue order, so vmcnt(L) <=> this wave's current-
// tile loads landed; barrier#1 makes that true for all waves. barrier#2 after
// the MFMAs keeps next iter's glds from overwriting buf[cur] early (all
// ds_reads consumed by MFMAs before it). sched_barrier(0) pins motion.
// No XCD swizzle here: R3 A/B showed it blew FETCH 41->70MB (wrong axis).
// ---------------------------------------------------------------------------
template<int EPI, int BN>
__global__ __launch_bounds__(256) void gemm_bt(
    const u16* __restrict__ A, const u16* __restrict__ Bt, int N, int K,
    u16* __restrict__ C, const float* __restrict__ bias,
    u16* __restrict__ qo, u16* __restrict__ ko, u16* __restrict__ vo,
    const float* __restrict__ bq, const float* __restrict__ bk,
    const float* __restrict__ bv)
{
    __shared__ __align__(16) u16 Asm[2][128 * 32];
    __shared__ __align__(16) u16 Bsm[2][BN * 32];
    const int tid  = threadIdx.x;
    const int lane = tid & 63;
    const int wave = tid >> 6;
    const int lrow = lane & 15, quad = lane >> 4;
    const int bm = blockIdx.x * 128, bn = blockIdx.y * BN;

    // staging: slot s covers row s>>2, kcols (s&3)*8..+7. LDS bytes = s*16.
    const int srow = tid >> 2;
    const int skol = (tid & 3) * 8;
    const u16* gA0 = A  + (size_t)(bm + srow) * K + skol;
    const u16* gA1 = gA0 + (size_t)64 * K;
    const u16* gB0 = Bt + (size_t)(bn + srow) * K + skol;
    const u16* gB1 = gB0 + (size_t)64 * K;   // used only when BN==128

    // wave -> 64 x (BN/2) output sub-tile
    const int wm = wave >> 1, wn = wave & 1;
    constexpr int NT = (BN == 128) ? 4 : 2;  // 16-col fragments per wave
    f32x4 acc[4][NT] = {};

    // prologue: issue tile 0 loads (LOADS outstanding; no wait yet)
    glds16(gA0, &Asm[0][(size_t)tid * 8]);
    glds16(gA1, &Asm[0][((size_t)tid + 256) * 8]);
    if constexpr (BN == 128) glds16(gB1, &Bsm[0][((size_t)tid + 256) * 8]);
    glds16(gB0, &Bsm[0][(size_t)tid * 8]);

    int cur = 0;
    for (int kt = 0; kt < K; kt += 32) {
        const int nxt = kt + 32;
        if (nxt < K) {   // issue next-tile loads; keep them in flight past bar
            glds16(gA0 + nxt, &Asm[cur ^ 1][(size_t)tid * 8]);
            glds16(gA1 + nxt, &Asm[cur ^ 1][((size_t)tid + 256) * 8]);
            if constexpr (BN == 128)
                glds16(gB1 + nxt, &Bsm[cur ^ 1][((size_t)tid + 256) * 8]);
            glds16(gB0 + nxt, &Bsm[cur ^ 1][(size_t)tid * 8]);
            // wait for OUR current-tile loads only (oldest L); next stays live
            if constexpr (BN == 128)
                asm volatile("s_waitcnt vmcnt(4)" ::: "memory");
            else
                asm volatile("s_waitcnt vmcnt(3)" ::: "memory");
        } else {
            asm volatile("s_waitcnt vmcnt(0)" ::: "memory");
        }
        __builtin_amdgcn_s_barrier();          // all waves: tile cur resident
        __builtin_amdgcn_sched_barrier(0);     // pin ds_reads below the wait

        bf16x8 af[4], bfr[NT];
        #pragma unroll
        for (int mt = 0; mt < 4; mt++)
            af[mt] = *(const bf16x8*)&Asm[cur][(wm * 64 + mt * 16 + lrow) * 32 + quad * 8];
        #pragma unroll
        for (int nt = 0; nt < NT; nt++)
            bfr[nt] = *(const bf16x8*)&Bsm[cur][(wn * (BN / 2) + nt * 16 + lrow) * 32 + quad * 8];
        #pragma unroll
        for (int mt = 0; mt < 4; mt++)
            #pragma unroll
            for (int nt = 0; nt < NT; nt++)
                acc[mt][nt] = __builtin_amdgcn_mfma_f32_16x16x32_bf16(
                    af[mt], bfr[nt], acc[mt][nt], 0, 0, 0);

        __builtin_amdgcn_sched_barrier(0);     // no ds_read sinks past barrier
        __builtin_amdgcn_s_barrier();          // buf[cur] reads done: safe to
        cur ^= 1;                              // overwrite next iteration
    }

    // epilogue: C/D layout col = lane&15, row = quad*4 + reg
    #pragma unroll
    for (int nt = 0; nt < NT; nt++) {
        int col = bn + wn * (BN / 2) + nt * 16 + lrow;
        int mat = 0, hh = 0, dd = 0;
        float bval;
        if (EPI == 2) {
            mat  = col >> 10; int dcol = col & 1023;
            hh = dcol >> 6;   dd = dcol & 63;
            const float* bp = (mat == 0) ? bq : ((mat == 1) ? bk : bv);
            bval = bp[dcol];
        } else {
            bval = bias[col];
        }
        #pragma unroll
        for (int mt = 0; mt < 4; mt++) {
            #pragma unroll
            for (int r = 0; r < 4; r++) {
                int row = bm + wm * 64 + mt * 16 + quad * 4 + r;
                float v = acc[mt][nt][r] + bval;
                if (EPI == 1) v = 0.5f * v * (1.0f + erff(v * 0.70710678118654752f));
                if (EPI == 2) {
                    int b = row >> 9, s = row & 511;   // b = batch within group
                    u16* dst = (mat == 0) ? qo : ((mat == 1) ? ko : vo);
                    dst[(((size_t)(b * 16 + hh)) * 512 + s) * 64 + dd] = f2b(v);
                } else {
                    C[(size_t)row * N + col] = f2b(v);
                }
            }
        }
    }
}

// ---------------------------------------------------------------------------
// Flash attention: 256 threads/block; q,k,v bf16 [8,16,512,64].
// scores = q@k^T/8 + mask*-1e9 + adj(fp32); softmax; @v.
// 2-phase pipeline: K double-buffered via glds; V reg-staged (issue-early /
// ds_write-late, T14); adj prefetched to regs; ONE barrier per KV-tile
// (between softmax and PV — covers all cross-wave hazards).
// XCD swizzle: batch-in-group b pinned to one XCD (2MB K/V + 1MB adj in L2).
// [unchanged from R3 — improved there; gets counted-vmcnt next round if the
//  GEMM schedule verifies]
// ---------------------------------------------------------------------------
__global__ __launch_bounds__(256) void attn_kernel(
    const u16* __restrict__ Q, const u16* __restrict__ Kb, const u16* __restrict__ Vb,
    const float* __restrict__ adj, const int* __restrict__ mask, u16* __restrict__ ctx)
{
    const int S = 512, H = 16;
    __shared__ __align__(16) u16 Ksm[2][32 * 64];   // [key][d]
    __shared__ __align__(16) u16 Vt [2][64 * 32];   // [d][key]
    __shared__ __align__(16) u16 Psm[4][16 * 32];   // per-wave P relayout buffer

    int tid = threadIdx.x, lane = tid & 63, wave = tid >> 6;
    int lrow = lane & 15, quad = lane >> 4;

    // work swizzle: orig%8 -> b, so each XCD owns one batch's K/V/adj
    int orig = (blockIdx.z * 16 + blockIdx.y) * 8 + blockIdx.x;
    int b  = orig & 7;
    int h  = (orig >> 3) & 15;
    int qt = orig >> 7;

    size_t headoff = ((size_t)(b * H + h)) * S * 64;
    const u16* qp = Q + headoff;
    const u16* kp = Kb + headoff;
    const u16* vp = Vb + headoff;
    const float* adjb = adj + (size_t)b * S * S;
    const int* maskb = mask + b * S;
    int q0 = qt * 64 + wave * 16;

    bf16x8 qf0 = *(const bf16x8*)(qp + (size_t)(q0 + lrow) * 64 + quad * 8);
    bf16x8 qf1 = *(const bf16x8*)(qp + (size_t)(q0 + lrow) * 64 + 32 + quad * 8);

    float m_run[4] = {-1e30f, -1e30f, -1e30f, -1e30f};
    float l_run[4] = {0.f, 0.f, 0.f, 0.f};
    f32x4 o[4] = {};

    int str = tid >> 3;          // 0..31  staging row (key)
    int stc = (tid & 7) * 8;     // 0..56  staging col (d)

    // prologue: stage K tile 0 (glds) + V tile 0 (regs)
    glds16(kp + (size_t)str * 64 + stc, &Ksm[0][str * 64 + stc]);
    bf16x8 vcur = *(const bf16x8*)(vp + (size_t)str * 64 + stc);
    __syncthreads();   // K tile 0 resident

    int cur = 0;
    for (int kt = 0; kt < S; kt += 32) {
        const int nxt = kt + 32;
        bf16x8 vnxt;
        if (nxt < S) {   // issue next K (glds) + next V (regs) first
            glds16(kp + (size_t)(nxt + str) * 64 + stc, &Ksm[cur ^ 1][str * 64 + stc]);
            vnxt = *(const bf16x8*)(vp + (size_t)(nxt + str) * 64 + stc);
        }
        // write CURRENT V tile (regs, loaded last iter) into Vt[cur]
        {
            const u16* tv = (const u16*)&vcur;
            #pragma unroll
            for (int j = 0; j < 8; j++) Vt[cur][(stc + j) * 32 + str] = tv[j];
        }
        // adj prefetch for current tile (hidden under QK^T)
        float adjv[2][4];
        #pragma unroll
        for (int f = 0; f < 2; f++)
            #pragma unroll
            for (int r = 0; r < 4; r++)
                adjv[f][r] = adjb[(size_t)(q0 + quad * 4 + r) * S + kt + f * 16 + lrow];

        f32x4 sc[2];
        #pragma unroll
        for (int f = 0; f < 2; f++) {
            f32x4 cf = {};
            bf16x8 kf0 = *(const bf16x8*)&Ksm[cur][(f * 16 + lrow) * 64 + quad * 8];
            bf16x8 kf1 = *(const bf16x8*)&Ksm[cur][(f * 16 + lrow) * 64 + 32 + quad * 8];
            cf = __builtin_amdgcn_mfma_f32_16x16x32_bf16(qf0, kf0, cf, 0, 0, 0);
            cf = __builtin_amdgcn_mfma_f32_16x16x32_bf16(qf1, kf1, cf, 0, 0, 0);
            int key = kt + f * 16 + lrow;
            float mterm = maskb[key] ? -1e9f : 0.0f;
            #pragma unroll
            for (int r = 0; r < 4; r++)
                sc[f][r] = cf[r] * 0.125f + mterm + adjv[f][r];
        }

        float mx[4], al[4], sm[4];
        #pragma unroll
        for (int r = 0; r < 4; r++) mx[r] = fmaxf(sc[0][r], sc[1][r]);
        #pragma unroll
        for (int mk = 1; mk < 16; mk <<= 1)
            #pragma unroll
            for (int r = 0; r < 4; r++) mx[r] = fmaxf(mx[r], __shfl_xor(mx[r], mk));
        #pragma unroll
        for (int r = 0; r < 4; r++) {
            float mn = fmaxf(m_run[r], mx[r]);
            al[r] = __expf(fminf(m_run[r] - mn, 0.f));
            m_run[r] = mn;
        }
        #pragma unroll
        for (int f = 0; f < 2; f++)
            #pragma unroll
            for (int r = 0; r < 4; r++)
                sc[f][r] = __expf(fminf(sc[f][r] - m_run[r], 0.f));
        #pragma unroll
        for (int r = 0; r < 4; r++) sm[r] = sc[0][r] + sc[1][r];
        #pragma unroll
        for (int mk = 1; mk < 16; mk <<= 1)
            #pragma unroll
            for (int r = 0; r < 4; r++) sm[r] += __shfl_xor(sm[r], mk);
        #pragma unroll
        for (int r = 0; r < 4; r++) l_run[r] = l_run[r] * al[r] + sm[r];
        #pragma unroll
        for (int nt = 0; nt < 4; nt++)
            #pragma unroll
            for (int r = 0; r < 4; r++) o[nt][r] *= al[r];

        #pragma unroll
        for (int f = 0; f < 2; f++)
            #pragma unroll
            for (int r = 0; r < 4; r++)
                Psm[wave][(quad * 4 + r) * 32 + f * 16 + lrow] = f2b(sc[f][r]);
        bf16x8 pa = *(const bf16x8*)&Psm[wave][lrow * 32 + quad * 8];

        __syncthreads();   // ONE barrier: Vt[cur] visible to all waves,
                           // K(nxt) glds drained (vmcnt 0), K(cur) reads done
        #pragma unroll
        for (int nt = 0; nt < 4; nt++) {
            bf16x8 vf = *(const bf16x8*)&Vt[cur][(nt * 16 + lrow) * 32 + quad * 8];
            o[nt] = __builtin_amdgcn_mfma_f32_16x16x32_bf16(pa, vf, o[nt], 0, 0, 0);
        }
        if (nxt < S) vcur = vnxt;
        cur ^= 1;
    }

    // ctx[b_local*512 + qrow, h*64 + d]
    #pragma unroll
    for (int nt = 0; nt < 4; nt++)
        #pragma unroll
        for (int r = 0; r < 4; r++) {
            int qrow = q0 + quad * 4 + r;
            ctx[((size_t)b * 512 + qrow) * 1024 + h * 64 + nt * 16 + lrow] =
                f2b(o[nt][r] / l_run[r]);
        }
}

// ---------------------------------------------------------------------------
// out = LayerNorm(X + Y): mean over D=1024, unbiased std (ddof=1), /(std+1e-6)
// MODE 0: X fp32, Y bf16, out bf16   MODE 1: X bf16, Y bf16, out fp32
// ---------------------------------------------------------------------------
template<int MODE>
__global__ __launch_bounds__(256) void add_ln(
    const void* __restrict__ Xv, const void* __restrict__ Yv,
    const float* __restrict__ gamma, const float* __restrict__ beta,
    void* __restrict__ outv)
{
    const int D = 1024;
    int row = blockIdx.x, tid = threadIdx.x;
    int lane = tid & 63, wave = tid >> 6;
    size_t base = (size_t)row * D + tid * 4;

    float x[4];
    if (MODE == 0) {
        float4 xf = *(const float4*)((const float*)Xv + base);
        u16x4  uy = *(const u16x4*)((const u16*)Yv + base);
        x[0] = xf.x + b2f(uy[0]); x[1] = xf.y + b2f(uy[1]);
        x[2] = xf.z + b2f(uy[2]); x[3] = xf.w + b2f(uy[3]);
    } else {
        u16x4 ux = *(const u16x4*)((const u16*)Xv + base);
        u16x4 uy = *(const u16x4*)((const u16*)Yv + base);
        #pragma unroll
        for (int j = 0; j < 4; j++) x[j] = b2f(ux[j]) + b2f(uy[j]);
    }

    float s = x[0] + x[1] + x[2] + x[3];
    #pragma unroll
    for (int mk = 1; mk < 64; mk <<= 1) s += __shfl_xor(s, mk);
    __shared__ float red[8];
    if (lane == 0) red[wave] = s;
    __syncthreads();
    float mean = (red[0] + red[1] + red[2] + red[3]) * (1.0f / 1024.0f);

    float c[4], q = 0.f;
    #pragma unroll
    for (int j = 0; j < 4; j++) { c[j] = x[j] - mean; q += c[j] * c[j]; }
    #pragma unroll
    for (int mk = 1; mk < 64; mk <<= 1) q += __shfl_xor(q, mk);
    if (lane == 0) red[4 + wave] = q;
    __syncthreads();
    float var = (red[4] + red[5] + red[6] + red[7]) * (1.0f / 1023.0f);
    float inv = 1.0f / (sqrtf(var) + 1e-6f);

    float4 g4 = *(const float4*)(gamma + tid * 4);
    float4 b4 = *(const float4*)(beta + tid * 4);
    float gv[4] = {g4.x, g4.y, g4.z, g4.w};
    float bv[4] = {b4.x, b4.y, b4.z, b4.w};
    if (MODE == 0) {
        u16x4 ov;
        #pragma unroll
        for (int j = 0; j < 4; j++) ov[j] = f2b(gv[j] * c[j] * inv + bv[j]);
        *(u16x4*)((u16*)outv + base) = ov;
    } else {
        float4 ov;
        ov.x = gv[0] * c[0] * inv + bv[0];
        ov.y = gv[1] * c[1] * inv + bv[1];
        ov.z = gv[2] * c[2] * inv + bv[2];
        ov.w = gv[3] * c[3] * inv + bv[3];
        *(float4*)((float*)outv + base) = ov;
    }
}

// ---------------------------------------------------------------------------
// Workspace (bf16 unless noted), 96 MB peak:
//   [ 0, 6) Wqkv_t  [ 6, 8) Wo_t  [ 8,16) W1_t  [16,24) W2_t
//   [24,56) out1 (16384x1024)
//   attn phase (per 8-batch group): [56,64) q [64,72) k [72,80) v
//     [80,88) ctx [88,96) x_bf16 (QKV A operand), then overwritten by attn_out
//   FFN phase (per 4096-row chunk): [56,88) hidden [88,96) ffn
// ---------------------------------------------------------------------------
extern "C" void kernel_launch(void* const* d_in, const int* in_sizes, int n_in,
                              void* d_out, int out_size, void* d_ws, size_t ws_size,
                              hipStream_t stream)
{
    const float* x    = (const float*)d_in[0];
    const int*   mask = (const int*)d_in[1];
    const float* adj  = (const float*)d_in[2];
    const float* Wq = (const float*)d_in[4];  const float* bq = (const float*)d_in[5];
    const float* Wk = (const float*)d_in[6];  const float* bk = (const float*)d_in[7];
    const float* Wv = (const float*)d_in[8];  const float* bv = (const float*)d_in[9];
    const float* Wo = (const float*)d_in[10]; const float* bo = (const float*)d_in[11];
    const float* W1 = (const float*)d_in[12]; const float* b1 = (const float*)d_in[13];
    const float* W2 = (const float*)d_in[14]; const float* b2 = (const float*)d_in[15];
    const float* gamma = (const float*)d_in[16];
    const float* beta  = (const float*)d_in[17];
    float* out = (float*)d_out;

    const size_t MB = 1024ull * 1024;
    char* w = (char*)d_ws;
    u16* Wqkv_t = (u16*)(w + 0 * MB);
    u16* Wo_t   = (u16*)(w + 6 * MB);
    u16* W1_t   = (u16*)(w + 8 * MB);
    u16* W2_t   = (u16*)(w + 16 * MB);
    u16* out1   = (u16*)(w + 24 * MB);
    u16* qg     = (u16*)(w + 56 * MB);
    u16* kg     = (u16*)(w + 64 * MB);
    u16* vg     = (u16*)(w + 72 * MB);
    u16* ctxg   = (u16*)(w + 80 * MB);
    u16* aog    = (u16*)(w + 88 * MB);   // x_bf16 during QKV, attn_out after Wo
    u16* hid    = (u16*)(w + 56 * MB);   // overlays q/k/v/ctx (dead in FFN phase)
    u16* ffn    = (u16*)(w + 88 * MB);   // overlays attn_out

    dim3 tb(32, 8);
    transpose_f32_bf16<<<dim3(32, 32),  tb, 0, stream>>>(Wq, Wqkv_t,                1024, 1024);
    transpose_f32_bf16<<<dim3(32, 32),  tb, 0, stream>>>(Wk, Wqkv_t + 1024ull*1024, 1024, 1024);
    transpose_f32_bf16<<<dim3(32, 32),  tb, 0, stream>>>(Wv, Wqkv_t + 2048ull*1024, 1024, 1024);
    transpose_f32_bf16<<<dim3(32, 32),  tb, 0, stream>>>(Wo, Wo_t,                  1024, 1024);
    transpose_f32_bf16<<<dim3(128, 32), tb, 0, stream>>>(W1, W1_t,                  1024, 4096);
    transpose_f32_bf16<<<dim3(32, 128), tb, 0, stream>>>(W2, W2_t,                  4096, 1024);

    // ---- attention phase: 4 groups of 8 batches (4096 rows each) ----
    for (int g = 0; g < 4; g++) {
        const float* xg = x + (size_t)g * 4096 * 1024;
        // x chunk -> bf16 (into aog region; dead until Wo writes it)
        cvt_f32_bf16<<<2048, 256, 0, stream>>>(xg, aog);
        gemm_bt<2, 128><<<dim3(32, 24), 256, 0, stream>>>(aog, Wqkv_t, 3072, 1024,
            nullptr, nullptr, qg, kg, vg, bq, bk, bv);
        attn_kernel<<<dim3(8, 16, 8), 256, 0, stream>>>(qg, kg, vg,
            adj + (size_t)g * 8 * 512 * 512, mask + g * 8 * 512, ctxg);
        gemm_bt<0, 64><<<dim3(32, 16), 256, 0, stream>>>(ctxg, Wo_t, 1024, 1024,
            aog, bo, nullptr, nullptr, nullptr, nullptr, nullptr, nullptr);
        add_ln<0><<<4096, 256, 0, stream>>>(xg, aog, gamma, beta,
            out1 + (size_t)g * 4096 * 1024);
    }

    // ---- FFN phase: 4 row chunks of 4096 ----
    for (int c = 0; c < 4; c++) {
        const u16* o1c = out1 + (size_t)c * 4096 * 1024;
        gemm_bt<1, 128><<<dim3(32, 32), 256, 0, stream>>>(o1c, W1_t, 4096, 1024,
            hid, b1, nullptr, nullptr, nullptr, nullptr, nullptr, nullptr);
        gemm_bt<0, 64><<<dim3(32, 16), 256, 0, stream>>>(hid, W2_t, 1024, 4096,
            ffn, b2, nullptr, nullptr, nullptr, nullptr, nullptr, nullptr);
        add_ln<1><<<4096, 256, 0, stream>>>(o1c, ffn, gamma, beta,
            out + (size_t)c * 4096 * 1024);
    }
}